// Round 10
// baseline (2062.126 us; speedup 1.0000x reference)
//
#include <hip/hip_runtime.h>

typedef _Float16 h16;
typedef __attribute__((ext_vector_type(4))) _Float16 h16x4;
typedef __attribute__((ext_vector_type(8))) _Float16 h16x8;
typedef __attribute__((ext_vector_type(4))) float f32x4;

#define QSCALE 0.25505653882616254f   // 32^-0.5 * log2(e)  (folded into Wq, bq)
#define LOG2E  1.4426950408889634f    // folded into biasF
#define MFMA16(a, b, c) __builtin_amdgcn_mfma_f32_16x16x16f16(a, b, c, 0, 0, 0)
#define MFMA32(a, b, c) __builtin_amdgcn_mfma_f32_16x16x32_f16(a, b, c, 0, 0, 0)

// workspace layout (bytes)
#define O_BYTES 205520896ULL              // 200704*512*2 (pre-proj output, fp16)
#define W1F_OFF (O_BYTES)                 // w1F fp16 fragment-packed: 1572864
#define W2T_OFF (W1F_OFF + 1572864ULL)    // w2T fp16 [512 out][512 k]: 524288
#define BF_OFF  (W2T_OFF + 524288ULL)     // biasF f32 frag-packed [16][4qt][4jt][64lane]x4: 262144

// ---------------- fused prep: w2 transpose | w1 fragment-pack | bias fragment-pack ----------------
__global__ __launch_bounds__(256) void wa_prep(
    const float* __restrict__ qkv_w, const float* __restrict__ proj_w,
    const float* __restrict__ table,
    h16* __restrict__ w1F, h16* __restrict__ w2T, float* __restrict__ biasF) {
  __shared__ h16 T[32][33];
  const int b = blockIdx.x, tid = threadIdx.x;
  if (b < 256) {
    int tx = tid & 31, ty = tid >> 5;
    int bo = b & 15, bc = b >> 4;
    #pragma unroll
    for (int i = 0; i < 4; ++i) {
      int c = bc * 32 + ty + 8 * i, o = bo * 32 + tx;
      T[ty + 8 * i][tx] = (h16)proj_w[c * 512 + o];
    }
    __syncthreads();
    #pragma unroll
    for (int i = 0; i < 4; ++i) {
      int o_l = ty + 8 * i;
      w2T[(size_t)(bo * 32 + o_l) * 512 + bc * 32 + tx] = T[tx][o_l];
    }
  } else if (b < 640) {
    int chunk = (b - 256) * 256 + tid;          // 98304 chunks
    int lane = chunk & 63;
    int rest = chunk >> 6;
    int f  = rest % 12;
    int kt = (rest / 12) & 7;
    int wv = (rest / 96) & 3;
    int g  = rest / 384;
    int s = f >> 2, d = (f >> 1) & 1, ks = f & 1;
    int l15 = lane & 15, lg = lane >> 4;
    int o = s * 512 + g * 128 + wv * 32 + d * 16 + l15;
    int k0 = kt * 64 + ks * 32 + lg * 8;
    float sc = (s == 0) ? QSCALE : 1.0f;
    h16x8 v;
    #pragma unroll
    for (int e = 0; e < 8; ++e)
      v[e] = (h16)(qkv_w[(size_t)(k0 + e) * 1536 + o] * sc);
    *(h16x8*)(w1F + (size_t)chunk * 8) = v;
  } else {
    int t = (b - 640) * 256 + tid;              // 16384 float4s
    int lane = t & 63, jt = (t >> 6) & 3, qt = (t >> 8) & 3, head = t >> 10;
    int l15 = lane & 15, lg = lane >> 4;
    int q = qt * 16 + l15;
    float4 v;
    #pragma unroll
    for (int r = 0; r < 4; ++r) {
      int j = jt * 16 + lg * 4 + r;
      float val = -1e30f;
      if (j < 49 && q < 49) {
        int rel = (q / 7 - j / 7 + 6) * 13 + (q % 7 - j % 7 + 6);
        val = table[rel * 16 + head] * LOG2E;
      }
      ((float*)&v)[r] = val;
    }
    ((float4*)biasF)[t] = v;
  }
}

// ---------------- fused QKV projection + window attention ----------------
// grid: 4096 windows * 2 (XCD-swizzled); block 256 = 4 waves; each block runs TWO
// head-groups sequentially over one X staging. X staged as ONLY 49 real rows
// (50176 B LDS -> 3 blocks/CU); t=3 fragment rows CLAMP to row 48 (broadcast read,
// swizzle key 0) -- tokens 49..63 behave as token-48 copies, annihilated by the
// -1e30 bias (P=0) and the q<49 store mask. W frags = coalesced 1KB wave-loads
// from fragment-packed w1F, 2-deep pipelined. One barrier total. Softmax:
// max-free exp2(S'+bias'), row-sum via all-ones-A MFMA, frag-packed bias loads,
// direct O^T stores.
__global__ __launch_bounds__(256, 3) void wa_qkv_attn(
    const float* __restrict__ x, const float* __restrict__ qkv_b,
    const h16* __restrict__ w1F, const float* __restrict__ biasF,
    h16* __restrict__ O) {
  __shared__ __align__(16) char lds[50176];   // X: [49 rows][64 chunks of 16B], swizzled
  const int tid = threadIdx.x;
  const int wave = tid >> 6, lane = tid & 63;
  const int l15 = lane & 15, lg = lane >> 4;
  const int sw = l15 & 7;
  const int lbid = (blockIdx.x & 7) * 1024 + (blockIdx.x >> 3);  // XCD swizzle (8192 % 8 == 0)
  const int w = lbid >> 1, gp = lbid & 1;
  const size_t rowbase = (size_t)w * 49;

  // ---- stage X: rows 0..48 fp32 -> fp16 swizzled (no pad rows) ----
  #pragma unroll
  for (int p = 0; p < 13; ++p) {
    int idx = tid + p * 256;
    if (idx < 3136) {
      int r = idx >> 6, c = idx & 63;
      const float* src = x + (rowbase + r) * 512 + c * 8;
      float4 a = *(const float4*)(src);
      float4 bb = *(const float4*)(src + 4);
      h16x8 h = { (h16)a.x, (h16)a.y, (h16)a.z, (h16)a.w,
                  (h16)bb.x, (h16)bb.y, (h16)bb.z, (h16)bb.w };
      *(h16x8*)(lds + r * 1024 + ((c ^ (r & 7)) << 4)) = h;
    }
  }
  __syncthreads();   // the only barrier in the kernel

  // per-lane X read bases; t=3 clamps to row 48 (swizzle key 48&7 == 0)
  int xb[4], coA[4], coB[4];
  #pragma unroll
  for (int t = 0; t < 4; ++t) {
    int row = (t < 3) ? (16 * t + l15) : 48;
    int swt = (t < 3) ? sw : 0;
    xb[t] = row * 1024;
    coA[t] = ((lg ^ swt) << 4);
    coB[t] = (((4 + lg) ^ swt) << 4);
  }
  const h16x4 ones = (h16x4){(h16)1.f, (h16)1.f, (h16)1.f, (h16)1.f};
  const float4* bF4 = (const float4*)biasF;

#define WLOAD(DST, KT) {                                                   \
    _Pragma("unroll") for (int f = 0; f < 12; ++f)                         \
      DST[f] = *(const h16x8*)(wb + (size_t)(KT) * 6144 + f * 512); }

#define GSTEP(KT, W) {                                                     \
    h16x8 xf[4];                                                           \
    _Pragma("unroll") for (int t = 0; t < 4; ++t)                          \
      xf[t] = *(const h16x8*)(lds + xb[t] + coA[t] + (KT) * 128);          \
    __builtin_amdgcn_s_setprio(1);                                         \
    _Pragma("unroll") for (int d = 0; d < 2; ++d)                          \
    _Pragma("unroll") for (int t = 0; t < 4; ++t) {                        \
      accQ[d][t] = MFMA32(W[0 + d*2], xf[t], accQ[d][t]);                  \
      accK[d][t] = MFMA32(W[4 + d*2], xf[t], accK[d][t]);                  \
      accV[t][d] = MFMA32(xf[t], W[8 + d*2], accV[t][d]);                  \
    }                                                                      \
    __builtin_amdgcn_s_setprio(0);                                         \
    _Pragma("unroll") for (int t = 0; t < 4; ++t)                          \
      xf[t] = *(const h16x8*)(lds + xb[t] + coB[t] + (KT) * 128);          \
    __builtin_amdgcn_s_setprio(1);                                         \
    _Pragma("unroll") for (int d = 0; d < 2; ++d)                          \
    _Pragma("unroll") for (int t = 0; t < 4; ++t) {                        \
      accQ[d][t] = MFMA32(W[1 + d*2], xf[t], accQ[d][t]);                  \
      accK[d][t] = MFMA32(W[5 + d*2], xf[t], accK[d][t]);                  \
      accV[t][d] = MFMA32(xf[t], W[9 + d*2], accV[t][d]);                  \
    }                                                                      \
    __builtin_amdgcn_s_setprio(0); }

#define PROCESS_HEAD(G) {                                                  \
    const int head = (G) * 4 + wave;                                       \
    const h16* wb = w1F + ((size_t)((G) * 4 + wave) * 8) * 6144 + lane * 8;\
    f32x4 accQ[2][4], accK[2][4], accV[4][2];                              \
    _Pragma("unroll") for (int d = 0; d < 2; ++d)                          \
    _Pragma("unroll") for (int t = 0; t < 4; ++t) {                        \
      accQ[d][t] = (f32x4){0.f, 0.f, 0.f, 0.f};                            \
      accK[d][t] = (f32x4){0.f, 0.f, 0.f, 0.f};                            \
      accV[t][d] = (f32x4){0.f, 0.f, 0.f, 0.f};                            \
    }                                                                      \
    h16x8 WA[12], WB[12];                                                  \
    WLOAD(WA, 0);                                                          \
    for (int kt2 = 0; kt2 < 4; ++kt2) {                                    \
      WLOAD(WB, 2 * kt2 + 1);                                              \
      GSTEP(2 * kt2, WA);                                                  \
      if (kt2 < 3) WLOAD(WA, 2 * kt2 + 2);                                 \
      GSTEP(2 * kt2 + 1, WB);                                              \
    }                                                                      \
    float bq[2][4], bk[2][4], bv[2];                                       \
    _Pragma("unroll") for (int d = 0; d < 2; ++d) {                        \
      _Pragma("unroll") for (int r = 0; r < 4; ++r) {                      \
        bq[d][r] = qkv_b[head * 32 + 16 * d + 4 * lg + r] * QSCALE;        \
        bk[d][r] = qkv_b[512 + head * 32 + 16 * d + 4 * lg + r];           \
      }                                                                    \
      bv[d] = qkv_b[1024 + head * 32 + 16 * d + l15];                      \
    }                                                                      \
    h16x4 Qh[2][4], Kh[2][4], Vh[4][2];                                    \
    _Pragma("unroll") for (int d = 0; d < 2; ++d)                          \
    _Pragma("unroll") for (int t = 0; t < 4; ++t)                          \
    _Pragma("unroll") for (int r = 0; r < 4; ++r) {                        \
      Qh[d][t][r] = (h16)(accQ[d][t][r] + bq[d][r]);                       \
      Kh[d][t][r] = (h16)(accK[d][t][r] + bk[d][r]);                       \
      Vh[t][d][r] = (h16)(accV[t][d][r] + bv[d]);                          \
    }                                                                      \
    f32x4 st[4][4];                                                        \
    _Pragma("unroll") for (int a = 0; a < 4; ++a)                          \
    _Pragma("unroll") for (int bb = 0; bb < 4; ++bb)                       \
      st[a][bb] = (f32x4){0.f, 0.f, 0.f, 0.f};                             \
    __builtin_amdgcn_s_setprio(1);                                         \
    _Pragma("unroll") for (int d = 0; d < 2; ++d)                          \
    _Pragma("unroll") for (int jt = 0; jt < 4; ++jt)                       \
    _Pragma("unroll") for (int qt = 0; qt < 4; ++qt)                       \
      st[jt][qt] = MFMA16(Kh[d][jt], Qh[d][qt], st[jt][qt]);               \
    __builtin_amdgcn_s_setprio(0);                                         \
    h16x4 pf[4][4];                                                        \
    _Pragma("unroll") for (int qt = 0; qt < 4; ++qt)                       \
    _Pragma("unroll") for (int jt = 0; jt < 4; ++jt) {                     \
      float4 bvv = bF4[(head * 16 + qt * 4 + jt) * 64 + lane];             \
      h16x4 p;                                                             \
      _Pragma("unroll") for (int r = 0; r < 4; ++r)                        \
        p[r] = (h16)exp2f(st[jt][qt][r] + ((const float*)&bvv)[r]);        \
      pf[jt][qt] = p;                                                      \
    }                                                                      \
    f32x4 ss[4];                                                           \
    _Pragma("unroll") for (int qt = 0; qt < 4; ++qt)                       \
      ss[qt] = (f32x4){0.f, 0.f, 0.f, 0.f};                                \
    f32x4 ot[2][4];                                                        \
    _Pragma("unroll") for (int d = 0; d < 2; ++d)                          \
    _Pragma("unroll") for (int qt = 0; qt < 4; ++qt)                       \
      ot[d][qt] = (f32x4){0.f, 0.f, 0.f, 0.f};                             \
    __builtin_amdgcn_s_setprio(1);                                         \
    _Pragma("unroll") for (int jt = 0; jt < 4; ++jt)                       \
    _Pragma("unroll") for (int qt = 0; qt < 4; ++qt) {                     \
      ss[qt] = MFMA16(ones, pf[jt][qt], ss[qt]);                           \
      _Pragma("unroll") for (int d = 0; d < 2; ++d)                        \
        ot[d][qt] = MFMA16(Vh[jt][d], pf[jt][qt], ot[d][qt]);              \
    }                                                                      \
    __builtin_amdgcn_s_setprio(0);                                         \
    _Pragma("unroll") for (int qt = 0; qt < 4; ++qt) {                     \
      int q = 16 * qt + l15;                                               \
      float ri = 1.0f / ss[qt][0];                                         \
      if (q < 49) {                                                        \
        h16* gdst = O + (rowbase + q) * 512 + head * 32 + 4 * lg;          \
        _Pragma("unroll") for (int d = 0; d < 2; ++d) {                    \
          h16x4 ov;                                                        \
          _Pragma("unroll") for (int r = 0; r < 4; ++r)                    \
            ov[r] = (h16)(ot[d][qt][r] * ri);                              \
          *(h16x4*)(gdst + 16 * d) = ov;                                   \
        }                                                                  \
      }                                                                    \
    } }

  PROCESS_HEAD(gp * 2);
  PROCESS_HEAD(gp * 2 + 1);
#undef PROCESS_HEAD
#undef WLOAD
#undef GSTEP
}

// ---------------- output projection: out = O @ w2 + proj_b ----------------
// 128x128 tile, 4 waves of 64x64, BK=64, x32 MFMAs, swizzled LDS, reg prefetch.
__global__ __launch_bounds__(256, 3) void wa_proj(
    const h16* __restrict__ O, const h16* __restrict__ w2T,
    const float* __restrict__ proj_b, float* __restrict__ out) {
  __shared__ __align__(16) char lds[32768];
  char* Ac = lds;            // [128 rows][64 k] h16, swizzled
  char* Bc = lds + 16384;    // [128 cols][64 k] h16, swizzled
  const int tid = threadIdx.x;
  const int wave = tid >> 6, lane = tid & 63;
  const int l15 = lane & 15, lg = lane >> 4;
  const int lbid = (blockIdx.x & 7) * 784 + (blockIdx.x >> 3);  // XCD swizzle (6272 % 8 == 0)
  const int rowt = lbid >> 2, colt = lbid & 3;
  const int wr = wave >> 1, wc = wave & 1;

  f32x4 acc[4][4];
  #pragma unroll
  for (int a = 0; a < 4; ++a)
    #pragma unroll
    for (int b = 0; b < 4; ++b) acc[a][b] = (f32x4){0.f, 0.f, 0.f, 0.f};

  h16x8 pre[8];
  #pragma unroll
  for (int p = 0; p < 8; ++p) {          // prologue load tile 0
    int idx = tid + p * 256;
    int r = (idx >> 3) & 127, c = idx & 7;
    pre[p] = (idx < 1024)
        ? *(const h16x8*)(O   + (size_t)(rowt * 128 + r) * 512 + c * 8)
        : *(const h16x8*)(w2T + (size_t)(colt * 128 + r) * 512 + c * 8);
  }
  #pragma unroll
  for (int p = 0; p < 8; ++p) {
    int idx = tid + p * 256;
    int r = (idx >> 3) & 127, c = idx & 7;
    char* dst = ((idx < 1024) ? Ac : Bc) + r * 128 + ((c ^ (r & 7)) << 4);
    *(h16x8*)dst = pre[p];
  }
  __syncthreads();

  for (int kt = 0; kt < 8; ++kt) {
    if (kt < 7) {
      #pragma unroll
      for (int p = 0; p < 8; ++p) {
        int idx = tid + p * 256;
        int r = (idx >> 3) & 127, c = idx & 7;
        pre[p] = (idx < 1024)
            ? *(const h16x8*)(O   + (size_t)(rowt * 128 + r) * 512 + (kt + 1) * 64 + c * 8)
            : *(const h16x8*)(w2T + (size_t)(colt * 128 + r) * 512 + (kt + 1) * 64 + c * 8);
      }
    }
    #pragma unroll
    for (int kh = 0; kh < 2; ++kh) {
      const int cc = kh * 4 + lg;
      const int sw = (l15 & 7);
      h16x8 af[4], bf[4];
      #pragma unroll
      for (int mt = 0; mt < 4; ++mt) {
        int r = wr * 64 + 16 * mt + l15;
        af[mt] = *(const h16x8*)(Ac + r * 128 + ((cc ^ sw) << 4));
      }
      #pragma unroll
      for (int nt = 0; nt < 4; ++nt) {
        int r = wc * 64 + 16 * nt + l15;
        bf[nt] = *(const h16x8*)(Bc + r * 128 + ((cc ^ sw) << 4));
      }
      __builtin_amdgcn_s_setprio(1);
      #pragma unroll
      for (int mt = 0; mt < 4; ++mt)
        #pragma unroll
        for (int nt = 0; nt < 4; ++nt)
          acc[mt][nt] = MFMA32(af[mt], bf[nt], acc[mt][nt]);
      __builtin_amdgcn_s_setprio(0);
    }
    __syncthreads();
    if (kt < 7) {
      #pragma unroll
      for (int p = 0; p < 8; ++p) {
        int idx = tid + p * 256;
        int r = (idx >> 3) & 127, c = idx & 7;
        char* dst = ((idx < 1024) ? Ac : Bc) + r * 128 + ((c ^ (r & 7)) << 4);
        *(h16x8*)dst = pre[p];
      }
      __syncthreads();
    }
  }
  #pragma unroll
  for (int nt = 0; nt < 4; ++nt) {
    int col = colt * 128 + wc * 64 + nt * 16 + l15;
    float pb = proj_b[col];
    #pragma unroll
    for (int mt = 0; mt < 4; ++mt) {
      int row = rowt * 128 + wr * 64 + mt * 16 + 4 * lg;
      #pragma unroll
      for (int r = 0; r < 4; ++r)
        out[(size_t)(row + r) * 512 + col] = acc[mt][nt][r] + pb;
    }
  }
}

extern "C" void kernel_launch(void* const* d_in, const int* in_sizes, int n_in,
                              void* d_out, int out_size, void* d_ws, size_t ws_size,
                              hipStream_t stream) {
  const float* x          = (const float*)d_in[0];
  const float* qkv_w      = (const float*)d_in[1];
  const float* qkv_b      = (const float*)d_in[2];
  const float* proj_w     = (const float*)d_in[3];
  const float* proj_b     = (const float*)d_in[4];
  const float* bias_table = (const float*)d_in[5];
  float* out = (float*)d_out;

  char* ws = (char*)d_ws;
  h16*   O     = (h16*)ws;
  h16*   w1F   = (h16*)(ws + W1F_OFF);
  h16*   w2T   = (h16*)(ws + W2T_OFF);
  float* biasF = (float*)(ws + BF_OFF);

  wa_prep<<<704, 256, 0, stream>>>(qkv_w, proj_w, bias_table, w1F, w2T, biasF);
  wa_qkv_attn<<<8192, 256, 0, stream>>>(x, qkv_b, w1F, biasF, O);
  wa_proj<<<1568 * 4, 256, 0, stream>>>(O, w2T, proj_b, out);
}

// Round 11
// 701.400 us; speedup vs baseline: 2.9400x; 2.9400x over previous
//
#include <hip/hip_runtime.h>

typedef _Float16 h16;
typedef __attribute__((ext_vector_type(4))) _Float16 h16x4;
typedef __attribute__((ext_vector_type(8))) _Float16 h16x8;
typedef __attribute__((ext_vector_type(4))) float f32x4;

#define QSCALE 0.25505653882616254f   // 32^-0.5 * log2(e)  (folded into Wq, bq)
#define LOG2E  1.4426950408889634f    // folded into biasF
#define MFMA16(a, b, c) __builtin_amdgcn_mfma_f32_16x16x16f16(a, b, c, 0, 0, 0)
#define MFMA32(a, b, c) __builtin_amdgcn_mfma_f32_16x16x32_f16(a, b, c, 0, 0, 0)

// workspace layout (bytes)
#define O_BYTES 205520896ULL              // 200704*512*2 (pre-proj output, fp16)
#define W1F_OFF (O_BYTES)                 // w1F fp16 fragment-packed: 1572864
#define W2T_OFF (W1F_OFF + 1572864ULL)    // w2T fp16 [512 out][512 k]: 524288
#define BF_OFF  (W2T_OFF + 524288ULL)     // biasF f32 frag-packed [16][4qt][4jt][64lane]x4: 262144

// ---------------- fused prep: w2 transpose | w1 fragment-pack | bias fragment-pack ----------------
__global__ __launch_bounds__(256) void wa_prep(
    const float* __restrict__ qkv_w, const float* __restrict__ proj_w,
    const float* __restrict__ table,
    h16* __restrict__ w1F, h16* __restrict__ w2T, float* __restrict__ biasF) {
  __shared__ h16 T[32][33];
  const int b = blockIdx.x, tid = threadIdx.x;
  if (b < 256) {
    int tx = tid & 31, ty = tid >> 5;
    int bo = b & 15, bc = b >> 4;
    #pragma unroll
    for (int i = 0; i < 4; ++i) {
      int c = bc * 32 + ty + 8 * i, o = bo * 32 + tx;
      T[ty + 8 * i][tx] = (h16)proj_w[c * 512 + o];
    }
    __syncthreads();
    #pragma unroll
    for (int i = 0; i < 4; ++i) {
      int o_l = ty + 8 * i;
      w2T[(size_t)(bo * 32 + o_l) * 512 + bc * 32 + tx] = T[tx][o_l];
    }
  } else if (b < 640) {
    int chunk = (b - 256) * 256 + tid;          // 98304 chunks
    int lane = chunk & 63;
    int rest = chunk >> 6;
    int f  = rest % 12;
    int kt = (rest / 12) & 7;
    int wv = (rest / 96) & 3;
    int g  = rest / 384;
    int s = f >> 2, d = (f >> 1) & 1, ks = f & 1;
    int l15 = lane & 15, lg = lane >> 4;
    int o = s * 512 + g * 128 + wv * 32 + d * 16 + l15;
    int k0 = kt * 64 + ks * 32 + lg * 8;
    float sc = (s == 0) ? QSCALE : 1.0f;
    h16x8 v;
    #pragma unroll
    for (int e = 0; e < 8; ++e)
      v[e] = (h16)(qkv_w[(size_t)(k0 + e) * 1536 + o] * sc);
    *(h16x8*)(w1F + (size_t)chunk * 8) = v;
  } else {
    int t = (b - 640) * 256 + tid;              // 16384 float4s
    int lane = t & 63, jt = (t >> 6) & 3, qt = (t >> 8) & 3, head = t >> 10;
    int l15 = lane & 15, lg = lane >> 4;
    int q = qt * 16 + l15;
    float4 v;
    #pragma unroll
    for (int r = 0; r < 4; ++r) {
      int j = jt * 16 + lg * 4 + r;
      float val = -1e30f;
      if (j < 49 && q < 49) {
        int rel = (q / 7 - j / 7 + 6) * 13 + (q % 7 - j % 7 + 6);
        val = table[rel * 16 + head] * LOG2E;
      }
      ((float*)&v)[r] = val;
    }
    ((float4*)biasF)[t] = v;
  }
}

// ---------------- fused QKV projection + window attention ----------------
// grid: 4096 windows * 2 (XCD-swizzled); block 256 = 4 waves; each block runs TWO
// head-groups sequentially over one X staging. X staged as only the 49 real rows
// (50176 B LDS); t=3 fragment rows CLAMP to row 48 (broadcast read, swizzle key 0) --
// tokens 49..63 behave as token-48 copies, annihilated by the -1e30 bias (P=0) and
// the q<49 store mask. W frags = coalesced 1KB wave-loads from fragment-packed w1F,
// 2-deep pipelined. One barrier total. Softmax: max-free exp2 with log2e pre-folded;
// BIAS FOLDED INTO QK^T as the C-init of the first MFMA (no epilogue adds);
// row-sum via all-ones-A MFMA; direct O^T stores.
// NOTE: occupancy ceiling is 2 blocks/CU -- 8 waves x ~216 unified regs = 1728 <= 2048/CU;
// __launch_bounds__(256,3) would cap waves at ~170 regs and force a catastrophic spill
// (round-10 lesson: per-SIMD pool is 512 regs, not 2048).
__global__ __launch_bounds__(256, 2) void wa_qkv_attn(
    const float* __restrict__ x, const float* __restrict__ qkv_b,
    const h16* __restrict__ w1F, const float* __restrict__ biasF,
    h16* __restrict__ O) {
  __shared__ __align__(16) char lds[50176];   // X: [49 rows][64 chunks of 16B], swizzled
  const int tid = threadIdx.x;
  const int wave = tid >> 6, lane = tid & 63;
  const int l15 = lane & 15, lg = lane >> 4;
  const int sw = l15 & 7;
  const int lbid = (blockIdx.x & 7) * 1024 + (blockIdx.x >> 3);  // XCD swizzle (8192 % 8 == 0)
  const int w = lbid >> 1, gp = lbid & 1;
  const size_t rowbase = (size_t)w * 49;

  // ---- stage X: rows 0..48 fp32 -> fp16 swizzled (no pad rows) ----
  #pragma unroll
  for (int p = 0; p < 13; ++p) {
    int idx = tid + p * 256;
    if (idx < 3136) {
      int r = idx >> 6, c = idx & 63;
      const float* src = x + (rowbase + r) * 512 + c * 8;
      float4 a = *(const float4*)(src);
      float4 bb = *(const float4*)(src + 4);
      h16x8 h = { (h16)a.x, (h16)a.y, (h16)a.z, (h16)a.w,
                  (h16)bb.x, (h16)bb.y, (h16)bb.z, (h16)bb.w };
      *(h16x8*)(lds + r * 1024 + ((c ^ (r & 7)) << 4)) = h;
    }
  }
  __syncthreads();   // the only barrier in the kernel

  // per-lane X read bases; t=3 clamps to row 48 (swizzle key 48&7 == 0)
  int xb[4], coA[4], coB[4];
  #pragma unroll
  for (int t = 0; t < 4; ++t) {
    int row = (t < 3) ? (16 * t + l15) : 48;
    int swt = (t < 3) ? sw : 0;
    xb[t] = row * 1024;
    coA[t] = ((lg ^ swt) << 4);
    coB[t] = (((4 + lg) ^ swt) << 4);
  }
  const h16x4 ones = (h16x4){(h16)1.f, (h16)1.f, (h16)1.f, (h16)1.f};
  const float4* bF4 = (const float4*)biasF;

#define WLOAD(DST, KT) {                                                   \
    _Pragma("unroll") for (int f = 0; f < 12; ++f)                         \
      DST[f] = *(const h16x8*)(wb + (size_t)(KT) * 6144 + f * 512); }

#define GSTEP(KT, W) {                                                     \
    h16x8 xf[4];                                                           \
    _Pragma("unroll") for (int t = 0; t < 4; ++t)                          \
      xf[t] = *(const h16x8*)(lds + xb[t] + coA[t] + (KT) * 128);          \
    __builtin_amdgcn_s_setprio(1);                                         \
    _Pragma("unroll") for (int d = 0; d < 2; ++d)                          \
    _Pragma("unroll") for (int t = 0; t < 4; ++t) {                        \
      accQ[d][t] = MFMA32(W[0 + d*2], xf[t], accQ[d][t]);                  \
      accK[d][t] = MFMA32(W[4 + d*2], xf[t], accK[d][t]);                  \
      accV[t][d] = MFMA32(xf[t], W[8 + d*2], accV[t][d]);                  \
    }                                                                      \
    __builtin_amdgcn_s_setprio(0);                                         \
    _Pragma("unroll") for (int t = 0; t < 4; ++t)                          \
      xf[t] = *(const h16x8*)(lds + xb[t] + coB[t] + (KT) * 128);          \
    __builtin_amdgcn_s_setprio(1);                                         \
    _Pragma("unroll") for (int d = 0; d < 2; ++d)                          \
    _Pragma("unroll") for (int t = 0; t < 4; ++t) {                        \
      accQ[d][t] = MFMA32(W[1 + d*2], xf[t], accQ[d][t]);                  \
      accK[d][t] = MFMA32(W[5 + d*2], xf[t], accK[d][t]);                  \
      accV[t][d] = MFMA32(xf[t], W[9 + d*2], accV[t][d]);                  \
    }                                                                      \
    __builtin_amdgcn_s_setprio(0); }

#define PROCESS_HEAD(G) {                                                  \
    const int head = (G) * 4 + wave;                                       \
    const h16* wb = w1F + ((size_t)((G) * 4 + wave) * 8) * 6144 + lane * 8;\
    f32x4 accQ[2][4], accK[2][4], accV[4][2];                              \
    _Pragma("unroll") for (int d = 0; d < 2; ++d)                          \
    _Pragma("unroll") for (int t = 0; t < 4; ++t) {                        \
      accQ[d][t] = (f32x4){0.f, 0.f, 0.f, 0.f};                            \
      accK[d][t] = (f32x4){0.f, 0.f, 0.f, 0.f};                            \
      accV[t][d] = (f32x4){0.f, 0.f, 0.f, 0.f};                            \
    }                                                                      \
    h16x8 WA[12], WB[12];                                                  \
    WLOAD(WA, 0);                                                          \
    for (int kt2 = 0; kt2 < 4; ++kt2) {                                    \
      WLOAD(WB, 2 * kt2 + 1);                                              \
      GSTEP(2 * kt2, WA);                                                  \
      if (kt2 < 3) WLOAD(WA, 2 * kt2 + 2);                                 \
      GSTEP(2 * kt2 + 1, WB);                                              \
    }                                                                      \
    float bq[2][4], bk[2][4], bv[2];                                       \
    _Pragma("unroll") for (int d = 0; d < 2; ++d) {                        \
      _Pragma("unroll") for (int r = 0; r < 4; ++r) {                      \
        bq[d][r] = qkv_b[head * 32 + 16 * d + 4 * lg + r] * QSCALE;        \
        bk[d][r] = qkv_b[512 + head * 32 + 16 * d + 4 * lg + r];           \
      }                                                                    \
      bv[d] = qkv_b[1024 + head * 32 + 16 * d + l15];                      \
    }                                                                      \
    h16x4 Qh[2][4], Kh[2][4], Vh[4][2];                                    \
    _Pragma("unroll") for (int d = 0; d < 2; ++d)                          \
    _Pragma("unroll") for (int t = 0; t < 4; ++t)                          \
    _Pragma("unroll") for (int r = 0; r < 4; ++r) {                        \
      Qh[d][t][r] = (h16)(accQ[d][t][r] + bq[d][r]);                       \
      Kh[d][t][r] = (h16)(accK[d][t][r] + bk[d][r]);                       \
      Vh[t][d][r] = (h16)(accV[t][d][r] + bv[d]);                          \
    }                                                                      \
    /* S^T = K Q^T with bias fragment as C-init of the d=0 MFMA */         \
    f32x4 st[4][4];                                                        \
    __builtin_amdgcn_s_setprio(1);                                         \
    _Pragma("unroll") for (int jt = 0; jt < 4; ++jt)                       \
    _Pragma("unroll") for (int qt = 0; qt < 4; ++qt) {                     \
      float4 bvv = bF4[(head * 16 + qt * 4 + jt) * 64 + lane];             \
      f32x4 c0 = { bvv.x, bvv.y, bvv.z, bvv.w };                           \
      st[jt][qt] = MFMA16(Kh[0][jt], Qh[0][qt], c0);                       \
      st[jt][qt] = MFMA16(Kh[1][jt], Qh[1][qt], st[jt][qt]);               \
    }                                                                      \
    __builtin_amdgcn_s_setprio(0);                                         \
    h16x4 pf[4][4];                                                        \
    _Pragma("unroll") for (int qt = 0; qt < 4; ++qt)                       \
    _Pragma("unroll") for (int jt = 0; jt < 4; ++jt) {                     \
      h16x4 p;                                                             \
      _Pragma("unroll") for (int r = 0; r < 4; ++r)                        \
        p[r] = (h16)exp2f(st[jt][qt][r]);                                  \
      pf[jt][qt] = p;                                                      \
    }                                                                      \
    f32x4 ss[4];                                                           \
    _Pragma("unroll") for (int qt = 0; qt < 4; ++qt)                       \
      ss[qt] = (f32x4){0.f, 0.f, 0.f, 0.f};                                \
    f32x4 ot[2][4];                                                        \
    _Pragma("unroll") for (int d = 0; d < 2; ++d)                          \
    _Pragma("unroll") for (int qt = 0; qt < 4; ++qt)                       \
      ot[d][qt] = (f32x4){0.f, 0.f, 0.f, 0.f};                             \
    __builtin_amdgcn_s_setprio(1);                                         \
    _Pragma("unroll") for (int jt = 0; jt < 4; ++jt)                       \
    _Pragma("unroll") for (int qt = 0; qt < 4; ++qt) {                     \
      ss[qt] = MFMA16(ones, pf[jt][qt], ss[qt]);                           \
      _Pragma("unroll") for (int d = 0; d < 2; ++d)                        \
        ot[d][qt] = MFMA16(Vh[jt][d], pf[jt][qt], ot[d][qt]);              \
    }                                                                      \
    __builtin_amdgcn_s_setprio(0);                                         \
    _Pragma("unroll") for (int qt = 0; qt < 4; ++qt) {                     \
      int q = 16 * qt + l15;                                               \
      float ri = 1.0f / ss[qt][0];                                         \
      if (q < 49) {                                                        \
        h16* gdst = O + (rowbase + q) * 512 + head * 32 + 4 * lg;          \
        _Pragma("unroll") for (int d = 0; d < 2; ++d) {                    \
          h16x4 ov;                                                        \
          _Pragma("unroll") for (int r = 0; r < 4; ++r)                    \
            ov[r] = (h16)(ot[d][qt][r] * ri);                              \
          *(h16x4*)(gdst + 16 * d) = ov;                                   \
        }                                                                  \
      }                                                                    \
    } }

  PROCESS_HEAD(gp * 2);
  PROCESS_HEAD(gp * 2 + 1);
#undef PROCESS_HEAD
#undef WLOAD
#undef GSTEP
}

// ---------------- output projection: out = O @ w2 + proj_b ----------------
// 128x128 tile, 4 waves of 64x64, BK=64, x32 MFMAs, swizzled LDS, reg prefetch.
__global__ __launch_bounds__(256, 3) void wa_proj(
    const h16* __restrict__ O, const h16* __restrict__ w2T,
    const float* __restrict__ proj_b, float* __restrict__ out) {
  __shared__ __align__(16) char lds[32768];
  char* Ac = lds;            // [128 rows][64 k] h16, swizzled
  char* Bc = lds + 16384;    // [128 cols][64 k] h16, swizzled
  const int tid = threadIdx.x;
  const int wave = tid >> 6, lane = tid & 63;
  const int l15 = lane & 15, lg = lane >> 4;
  const int lbid = (blockIdx.x & 7) * 784 + (blockIdx.x >> 3);  // XCD swizzle (6272 % 8 == 0)
  const int rowt = lbid >> 2, colt = lbid & 3;
  const int wr = wave >> 1, wc = wave & 1;

  f32x4 acc[4][4];
  #pragma unroll
  for (int a = 0; a < 4; ++a)
    #pragma unroll
    for (int b = 0; b < 4; ++b) acc[a][b] = (f32x4){0.f, 0.f, 0.f, 0.f};

  h16x8 pre[8];
  #pragma unroll
  for (int p = 0; p < 8; ++p) {          // prologue load tile 0
    int idx = tid + p * 256;
    int r = (idx >> 3) & 127, c = idx & 7;
    pre[p] = (idx < 1024)
        ? *(const h16x8*)(O   + (size_t)(rowt * 128 + r) * 512 + c * 8)
        : *(const h16x8*)(w2T + (size_t)(colt * 128 + r) * 512 + c * 8);
  }
  #pragma unroll
  for (int p = 0; p < 8; ++p) {
    int idx = tid + p * 256;
    int r = (idx >> 3) & 127, c = idx & 7;
    char* dst = ((idx < 1024) ? Ac : Bc) + r * 128 + ((c ^ (r & 7)) << 4);
    *(h16x8*)dst = pre[p];
  }
  __syncthreads();

  for (int kt = 0; kt < 8; ++kt) {
    if (kt < 7) {
      #pragma unroll
      for (int p = 0; p < 8; ++p) {
        int idx = tid + p * 256;
        int r = (idx >> 3) & 127, c = idx & 7;
        pre[p] = (idx < 1024)
            ? *(const h16x8*)(O   + (size_t)(rowt * 128 + r) * 512 + (kt + 1) * 64 + c * 8)
            : *(const h16x8*)(w2T + (size_t)(colt * 128 + r) * 512 + (kt + 1) * 64 + c * 8);
      }
    }
    #pragma unroll
    for (int kh = 0; kh < 2; ++kh) {
      const int cc = kh * 4 + lg;
      const int sw = (l15 & 7);
      h16x8 af[4], bf[4];
      #pragma unroll
      for (int mt = 0; mt < 4; ++mt) {
        int r = wr * 64 + 16 * mt + l15;
        af[mt] = *(const h16x8*)(Ac + r * 128 + ((cc ^ sw) << 4));
      }
      #pragma unroll
      for (int nt = 0; nt < 4; ++nt) {
        int r = wc * 64 + 16 * nt + l15;
        bf[nt] = *(const h16x8*)(Bc + r * 128 + ((cc ^ sw) << 4));
      }
      __builtin_amdgcn_s_setprio(1);
      #pragma unroll
      for (int mt = 0; mt < 4; ++mt)
        #pragma unroll
        for (int nt = 0; nt < 4; ++nt)
          acc[mt][nt] = MFMA32(af[mt], bf[nt], acc[mt][nt]);
      __builtin_amdgcn_s_setprio(0);
    }
    __syncthreads();
    if (kt < 7) {
      #pragma unroll
      for (int p = 0; p < 8; ++p) {
        int idx = tid + p * 256;
        int r = (idx >> 3) & 127, c = idx & 7;
        char* dst = ((idx < 1024) ? Ac : Bc) + r * 128 + ((c ^ (r & 7)) << 4);
        *(h16x8*)dst = pre[p];
      }
      __syncthreads();
    }
  }
  #pragma unroll
  for (int nt = 0; nt < 4; ++nt) {
    int col = colt * 128 + wc * 64 + nt * 16 + l15;
    float pb = proj_b[col];
    #pragma unroll
    for (int mt = 0; mt < 4; ++mt) {
      int row = rowt * 128 + wr * 64 + mt * 16 + 4 * lg;
      #pragma unroll
      for (int r = 0; r < 4; ++r)
        out[(size_t)(row + r) * 512 + col] = acc[mt][nt][r] + pb;
    }
  }
}

extern "C" void kernel_launch(void* const* d_in, const int* in_sizes, int n_in,
                              void* d_out, int out_size, void* d_ws, size_t ws_size,
                              hipStream_t stream) {
  const float* x          = (const float*)d_in[0];
  const float* qkv_w      = (const float*)d_in[1];
  const float* qkv_b      = (const float*)d_in[2];
  const float* proj_w     = (const float*)d_in[3];
  const float* proj_b     = (const float*)d_in[4];
  const float* bias_table = (const float*)d_in[5];
  float* out = (float*)d_out;

  char* ws = (char*)d_ws;
  h16*   O     = (h16*)ws;
  h16*   w1F   = (h16*)(ws + W1F_OFF);
  h16*   w2T   = (h16*)(ws + W2T_OFF);
  float* biasF = (float*)(ws + BF_OFF);

  wa_prep<<<704, 256, 0, stream>>>(qkv_w, proj_w, bias_table, w1F, w2T, biasF);
  wa_qkv_attn<<<8192, 256, 0, stream>>>(x, qkv_b, w1F, biasF, O);
  wa_proj<<<1568 * 4, 256, 0, stream>>>(O, w2T, proj_b, out);
}

// Round 12
// 696.906 us; speedup vs baseline: 2.9590x; 1.0064x over previous
//
#include <hip/hip_runtime.h>

typedef _Float16 h16;
typedef __attribute__((ext_vector_type(4))) _Float16 h16x4;
typedef __attribute__((ext_vector_type(8))) _Float16 h16x8;
typedef __attribute__((ext_vector_type(4))) float f32x4;

#define QSCALE 0.25505653882616254f   // 32^-0.5 * log2(e)  (folded into Wq, bq)
#define LOG2E  1.4426950408889634f    // folded into biasF
#define MFMA16(a, b, c) __builtin_amdgcn_mfma_f32_16x16x16f16(a, b, c, 0, 0, 0)
#define MFMA32(a, b, c) __builtin_amdgcn_mfma_f32_16x16x32_f16(a, b, c, 0, 0, 0)

// workspace layout (bytes)
#define O_BYTES 205520896ULL              // 200704*512*2 (pre-proj output, fp16)
#define W1F_OFF (O_BYTES)                 // w1F fp16 fragment-packed: 1572864
#define W2T_OFF (W1F_OFF + 1572864ULL)    // w2T fp16 [512 out][512 k]: 524288
#define BF_OFF  (W2T_OFF + 524288ULL)     // biasF f32 frag-packed [16][4qt][4jt][64lane]x4: 262144

// ---------------- fused prep: w2 transpose | w1 fragment-pack | bias fragment-pack ----------------
__global__ __launch_bounds__(256) void wa_prep(
    const float* __restrict__ qkv_w, const float* __restrict__ proj_w,
    const float* __restrict__ table,
    h16* __restrict__ w1F, h16* __restrict__ w2T, float* __restrict__ biasF) {
  __shared__ h16 T[32][33];
  const int b = blockIdx.x, tid = threadIdx.x;
  if (b < 256) {
    int tx = tid & 31, ty = tid >> 5;
    int bo = b & 15, bc = b >> 4;
    #pragma unroll
    for (int i = 0; i < 4; ++i) {
      int c = bc * 32 + ty + 8 * i, o = bo * 32 + tx;
      T[ty + 8 * i][tx] = (h16)proj_w[c * 512 + o];
    }
    __syncthreads();
    #pragma unroll
    for (int i = 0; i < 4; ++i) {
      int o_l = ty + 8 * i;
      w2T[(size_t)(bo * 32 + o_l) * 512 + bc * 32 + tx] = T[tx][o_l];
    }
  } else if (b < 640) {
    int chunk = (b - 256) * 256 + tid;          // 98304 chunks
    int lane = chunk & 63;
    int rest = chunk >> 6;
    int f  = rest % 12;
    int kt = (rest / 12) & 7;
    int wv = (rest / 96) & 3;
    int g  = rest / 384;
    int s = f >> 2, d = (f >> 1) & 1, ks = f & 1;
    int l15 = lane & 15, lg = lane >> 4;
    int o = s * 512 + g * 128 + wv * 32 + d * 16 + l15;
    int k0 = kt * 64 + ks * 32 + lg * 8;
    float sc = (s == 0) ? QSCALE : 1.0f;
    h16x8 v;
    #pragma unroll
    for (int e = 0; e < 8; ++e)
      v[e] = (h16)(qkv_w[(size_t)(k0 + e) * 1536 + o] * sc);
    *(h16x8*)(w1F + (size_t)chunk * 8) = v;
  } else {
    int t = (b - 640) * 256 + tid;              // 16384 float4s
    int lane = t & 63, jt = (t >> 6) & 3, qt = (t >> 8) & 3, head = t >> 10;
    int l15 = lane & 15, lg = lane >> 4;
    int q = qt * 16 + l15;
    float4 v;
    #pragma unroll
    for (int r = 0; r < 4; ++r) {
      int j = jt * 16 + lg * 4 + r;
      float val = -1e30f;
      if (j < 49 && q < 49) {
        int rel = (q / 7 - j / 7 + 6) * 13 + (q % 7 - j % 7 + 6);
        val = table[rel * 16 + head] * LOG2E;
      }
      ((float*)&v)[r] = val;
    }
    ((float4*)biasF)[t] = v;
  }
}

// ---------------- fused QKV projection + window attention ----------------
// grid: 4096 windows * 2 (XCD-swizzled); block 256 = 4 waves; each block runs TWO
// head-groups sequentially over one X staging (49 real rows, 50176 B LDS; t=3 frag
// rows clamp to row 48 -- pad tokens become token-48 copies, annihilated by -1e30
// bias and the q<49 store mask). Q, K, V computed as THREE SEQUENTIAL GEMM PASSES
// over LDS-X (acc 32 + W-dbuf 32 regs per pass instead of 96+96 fused) so per-wave
// unified regs ~<=170 -> __launch_bounds__(256,3) = 3 blocks/CU (round-10/11 lesson:
// per-SIMD pool is 512 regs; 2-block cfg was register-capped at 216/wave).
// SPILL TRIPWIRE: WRITE_SIZE must stay ~205 MB; >400 MB means allocator overflow.
// W frags = coalesced 1KB wave-loads from fragment-packed w1F, 2-deep pipelined.
// One barrier total. Softmax: max-free exp2 (log2e pre-folded), bias as QK^T C-init,
// row-sum via all-ones-A MFMA, direct O^T fragment stores.
__global__ __launch_bounds__(256, 3) void wa_qkv_attn(
    const float* __restrict__ x, const float* __restrict__ qkv_b,
    const h16* __restrict__ w1F, const float* __restrict__ biasF,
    h16* __restrict__ O) {
  __shared__ __align__(16) char lds[50176];   // X: [49 rows][64 chunks of 16B], swizzled
  const int tid = threadIdx.x;
  const int wave = tid >> 6, lane = tid & 63;
  const int l15 = lane & 15, lg = lane >> 4;
  const int sw = l15 & 7;
  const int lbid = (blockIdx.x & 7) * 1024 + (blockIdx.x >> 3);  // XCD swizzle (8192 % 8 == 0)
  const int w = lbid >> 1, gp = lbid & 1;
  const size_t rowbase = (size_t)w * 49;

  // ---- stage X: rows 0..48 fp32 -> fp16 swizzled (no pad rows) ----
  #pragma unroll
  for (int p = 0; p < 13; ++p) {
    int idx = tid + p * 256;
    if (idx < 3136) {
      int r = idx >> 6, c = idx & 63;
      const float* src = x + (rowbase + r) * 512 + c * 8;
      float4 a = *(const float4*)(src);
      float4 bb = *(const float4*)(src + 4);
      h16x8 h = { (h16)a.x, (h16)a.y, (h16)a.z, (h16)a.w,
                  (h16)bb.x, (h16)bb.y, (h16)bb.z, (h16)bb.w };
      *(h16x8*)(lds + r * 1024 + ((c ^ (r & 7)) << 4)) = h;
    }
  }
  __syncthreads();   // the only barrier in the kernel

  // per-lane X read byte-offsets (ks=0 half -> xbA, ks=1 half -> xbB);
  // t=3 clamps to row 48 (swizzle key 48&7 == 0)
  int xbA[4], xbB[4];
  #pragma unroll
  for (int t = 0; t < 4; ++t) {
    int row = (t < 3) ? (16 * t + l15) : 48;
    int swt = (t < 3) ? sw : 0;
    xbA[t] = row * 1024 + ((lg ^ swt) << 4);
    xbB[t] = row * 1024 + (((4 + lg) ^ swt) << 4);
  }
  const h16x4 ones = (h16x4){(h16)1.f, (h16)1.f, (h16)1.f, (h16)1.f};
  const float4* bF4 = (const float4*)biasF;

// load the 4 fragments (d*2+ks) of source S for k-tile KT -- 4 coalesced 1KB wave-loads
#define WLOAD4(DST, S, KT) {                                               \
    _Pragma("unroll") for (int f4 = 0; f4 < 4; ++f4)                       \
      DST[f4] = *(const h16x8*)(wb + (size_t)(KT) * 6144 + ((S)*4 + f4) * 512); }

// one k-tile step, W as A-operand (Q^T / K^T passes): ACC[d][t]
#define STEP_WA(KT, W, ACC) {                                              \
    h16x8 xf[4];                                                           \
    _Pragma("unroll") for (int t = 0; t < 4; ++t)                          \
      xf[t] = *(const h16x8*)(lds + xbA[t] + (KT) * 128);                  \
    __builtin_amdgcn_s_setprio(1);                                         \
    _Pragma("unroll") for (int d = 0; d < 2; ++d)                          \
    _Pragma("unroll") for (int t = 0; t < 4; ++t)                          \
      ACC[d][t] = MFMA32(W[d*2], xf[t], ACC[d][t]);                        \
    __builtin_amdgcn_s_setprio(0);                                         \
    _Pragma("unroll") for (int t = 0; t < 4; ++t)                          \
      xf[t] = *(const h16x8*)(lds + xbB[t] + (KT) * 128);                  \
    __builtin_amdgcn_s_setprio(1);                                         \
    _Pragma("unroll") for (int d = 0; d < 2; ++d)                          \
    _Pragma("unroll") for (int t = 0; t < 4; ++t)                          \
      ACC[d][t] = MFMA32(W[d*2 + 1], xf[t], ACC[d][t]);                    \
    __builtin_amdgcn_s_setprio(0); }

// one k-tile step, X as A-operand (V pass): ACC[t][d]
#define STEP_XA(KT, W, ACC) {                                              \
    h16x8 xf[4];                                                           \
    _Pragma("unroll") for (int t = 0; t < 4; ++t)                          \
      xf[t] = *(const h16x8*)(lds + xbA[t] + (KT) * 128);                  \
    __builtin_amdgcn_s_setprio(1);                                         \
    _Pragma("unroll") for (int d = 0; d < 2; ++d)                          \
    _Pragma("unroll") for (int t = 0; t < 4; ++t)                          \
      ACC[t][d] = MFMA32(xf[t], W[d*2], ACC[t][d]);                        \
    __builtin_amdgcn_s_setprio(0);                                         \
    _Pragma("unroll") for (int t = 0; t < 4; ++t)                          \
      xf[t] = *(const h16x8*)(lds + xbB[t] + (KT) * 128);                  \
    __builtin_amdgcn_s_setprio(1);                                         \
    _Pragma("unroll") for (int d = 0; d < 2; ++d)                          \
    _Pragma("unroll") for (int t = 0; t < 4; ++t)                          \
      ACC[t][d] = MFMA32(xf[t], W[d*2 + 1], ACC[t][d]);                    \
    __builtin_amdgcn_s_setprio(0); }

// full 512-deep pass over k, 2-deep W prefetch
#define GPASS(S, STEP, ACC) {                                              \
    h16x8 Wa[4], Wb[4];                                                    \
    WLOAD4(Wa, S, 0);                                                      \
    for (int kt2 = 0; kt2 < 4; ++kt2) {                                    \
      WLOAD4(Wb, S, 2 * kt2 + 1);                                          \
      STEP(2 * kt2, Wa, ACC);                                              \
      if (kt2 < 3) WLOAD4(Wa, S, 2 * kt2 + 2);                             \
      STEP(2 * kt2 + 1, Wb, ACC);                                          \
    } }

#define PROCESS_HEAD(G) {                                                  \
    const int head = (G) * 4 + wave;                                       \
    const h16* wb = w1F + ((size_t)((G) * 4 + wave) * 8) * 6144 + lane * 8;\
    h16x4 Qh[2][4], Kh[2][4], Vh[4][2];                                    \
    /* ---- pass Q ---- */ {                                               \
      f32x4 acc[2][4];                                                     \
      _Pragma("unroll") for (int d = 0; d < 2; ++d)                        \
      _Pragma("unroll") for (int t = 0; t < 4; ++t)                        \
        acc[d][t] = (f32x4){0.f, 0.f, 0.f, 0.f};                           \
      GPASS(0, STEP_WA, acc);                                              \
      _Pragma("unroll") for (int d = 0; d < 2; ++d) {                      \
        float bq[4];                                                       \
        _Pragma("unroll") for (int r = 0; r < 4; ++r)                      \
          bq[r] = qkv_b[head * 32 + 16 * d + 4 * lg + r] * QSCALE;         \
        _Pragma("unroll") for (int t = 0; t < 4; ++t)                      \
        _Pragma("unroll") for (int r = 0; r < 4; ++r)                      \
          Qh[d][t][r] = (h16)(acc[d][t][r] + bq[r]);                       \
      }                                                                    \
    }                                                                      \
    /* ---- pass K ---- */ {                                               \
      f32x4 acc[2][4];                                                     \
      _Pragma("unroll") for (int d = 0; d < 2; ++d)                        \
      _Pragma("unroll") for (int t = 0; t < 4; ++t)                        \
        acc[d][t] = (f32x4){0.f, 0.f, 0.f, 0.f};                           \
      GPASS(1, STEP_WA, acc);                                              \
      _Pragma("unroll") for (int d = 0; d < 2; ++d) {                      \
        float bk[4];                                                       \
        _Pragma("unroll") for (int r = 0; r < 4; ++r)                      \
          bk[r] = qkv_b[512 + head * 32 + 16 * d + 4 * lg + r];            \
        _Pragma("unroll") for (int t = 0; t < 4; ++t)                      \
        _Pragma("unroll") for (int r = 0; r < 4; ++r)                      \
          Kh[d][t][r] = (h16)(acc[d][t][r] + bk[r]);                       \
      }                                                                    \
    }                                                                      \
    /* ---- pass V ---- */ {                                               \
      f32x4 acc[4][2];                                                     \
      _Pragma("unroll") for (int t = 0; t < 4; ++t)                        \
      _Pragma("unroll") for (int d = 0; d < 2; ++d)                        \
        acc[t][d] = (f32x4){0.f, 0.f, 0.f, 0.f};                           \
      GPASS(2, STEP_XA, acc);                                              \
      _Pragma("unroll") for (int d = 0; d < 2; ++d) {                      \
        float bv = qkv_b[1024 + head * 32 + 16 * d + l15];                 \
        _Pragma("unroll") for (int t = 0; t < 4; ++t)                      \
        _Pragma("unroll") for (int r = 0; r < 4; ++r)                      \
          Vh[t][d][r] = (h16)(acc[t][d][r] + bv);                          \
      }                                                                    \
    }                                                                      \
    /* S^T = K Q^T with bias fragment as C-init */                         \
    f32x4 st[4][4];                                                        \
    __builtin_amdgcn_s_setprio(1);                                         \
    _Pragma("unroll") for (int jt = 0; jt < 4; ++jt)                       \
    _Pragma("unroll") for (int qt = 0; qt < 4; ++qt) {                     \
      float4 bvv = bF4[(head * 16 + qt * 4 + jt) * 64 + lane];             \
      f32x4 c0 = { bvv.x, bvv.y, bvv.z, bvv.w };                           \
      st[jt][qt] = MFMA16(Kh[0][jt], Qh[0][qt], c0);                       \
      st[jt][qt] = MFMA16(Kh[1][jt], Qh[1][qt], st[jt][qt]);               \
    }                                                                      \
    __builtin_amdgcn_s_setprio(0);                                         \
    h16x4 pf[4][4];                                                        \
    _Pragma("unroll") for (int qt = 0; qt < 4; ++qt)                       \
    _Pragma("unroll") for (int jt = 0; jt < 4; ++jt) {                     \
      h16x4 p;                                                             \
      _Pragma("unroll") for (int r = 0; r < 4; ++r)                        \
        p[r] = (h16)exp2f(st[jt][qt][r]);                                  \
      pf[jt][qt] = p;                                                      \
    }                                                                      \
    f32x4 ss[4];                                                           \
    _Pragma("unroll") for (int qt = 0; qt < 4; ++qt)                       \
      ss[qt] = (f32x4){0.f, 0.f, 0.f, 0.f};                                \
    f32x4 ot[2][4];                                                        \
    _Pragma("unroll") for (int d = 0; d < 2; ++d)                          \
    _Pragma("unroll") for (int qt = 0; qt < 4; ++qt)                       \
      ot[d][qt] = (f32x4){0.f, 0.f, 0.f, 0.f};                             \
    __builtin_amdgcn_s_setprio(1);                                         \
    _Pragma("unroll") for (int jt = 0; jt < 4; ++jt)                       \
    _Pragma("unroll") for (int qt = 0; qt < 4; ++qt) {                     \
      ss[qt] = MFMA16(ones, pf[jt][qt], ss[qt]);                           \
      _Pragma("unroll") for (int d = 0; d < 2; ++d)                        \
        ot[d][qt] = MFMA16(Vh[jt][d], pf[jt][qt], ot[d][qt]);              \
    }                                                                      \
    __builtin_amdgcn_s_setprio(0);                                         \
    _Pragma("unroll") for (int qt = 0; qt < 4; ++qt) {                     \
      int q = 16 * qt + l15;                                               \
      float ri = 1.0f / ss[qt][0];                                         \
      if (q < 49) {                                                        \
        h16* gdst = O + (rowbase + q) * 512 + head * 32 + 4 * lg;          \
        _Pragma("unroll") for (int d = 0; d < 2; ++d) {                    \
          h16x4 ov;                                                        \
          _Pragma("unroll") for (int r = 0; r < 4; ++r)                    \
            ov[r] = (h16)(ot[d][qt][r] * ri);                              \
          *(h16x4*)(gdst + 16 * d) = ov;                                   \
        }                                                                  \
      }                                                                    \
    } }

  PROCESS_HEAD(gp * 2);
  PROCESS_HEAD(gp * 2 + 1);
#undef PROCESS_HEAD
#undef GPASS
#undef STEP_WA
#undef STEP_XA
#undef WLOAD4
}

// ---------------- output projection: out = O @ w2 + proj_b ----------------
// 128x128 tile, 4 waves of 64x64, BK=64, x32 MFMAs, swizzled LDS, reg prefetch.
__global__ __launch_bounds__(256, 3) void wa_proj(
    const h16* __restrict__ O, const h16* __restrict__ w2T,
    const float* __restrict__ proj_b, float* __restrict__ out) {
  __shared__ __align__(16) char lds[32768];
  char* Ac = lds;            // [128 rows][64 k] h16, swizzled
  char* Bc = lds + 16384;    // [128 cols][64 k] h16, swizzled
  const int tid = threadIdx.x;
  const int wave = tid >> 6, lane = tid & 63;
  const int l15 = lane & 15, lg = lane >> 4;
  const int lbid = (blockIdx.x & 7) * 784 + (blockIdx.x >> 3);  // XCD swizzle (6272 % 8 == 0)
  const int rowt = lbid >> 2, colt = lbid & 3;
  const int wr = wave >> 1, wc = wave & 1;

  f32x4 acc[4][4];
  #pragma unroll
  for (int a = 0; a < 4; ++a)
    #pragma unroll
    for (int b = 0; b < 4; ++b) acc[a][b] = (f32x4){0.f, 0.f, 0.f, 0.f};

  h16x8 pre[8];
  #pragma unroll
  for (int p = 0; p < 8; ++p) {          // prologue load tile 0
    int idx = tid + p * 256;
    int r = (idx >> 3) & 127, c = idx & 7;
    pre[p] = (idx < 1024)
        ? *(const h16x8*)(O   + (size_t)(rowt * 128 + r) * 512 + c * 8)
        : *(const h16x8*)(w2T + (size_t)(colt * 128 + r) * 512 + c * 8);
  }
  #pragma unroll
  for (int p = 0; p < 8; ++p) {
    int idx = tid + p * 256;
    int r = (idx >> 3) & 127, c = idx & 7;
    char* dst = ((idx < 1024) ? Ac : Bc) + r * 128 + ((c ^ (r & 7)) << 4);
    *(h16x8*)dst = pre[p];
  }
  __syncthreads();

  for (int kt = 0; kt < 8; ++kt) {
    if (kt < 7) {
      #pragma unroll
      for (int p = 0; p < 8; ++p) {
        int idx = tid + p * 256;
        int r = (idx >> 3) & 127, c = idx & 7;
        pre[p] = (idx < 1024)
            ? *(const h16x8*)(O   + (size_t)(rowt * 128 + r) * 512 + (kt + 1) * 64 + c * 8)
            : *(const h16x8*)(w2T + (size_t)(colt * 128 + r) * 512 + (kt + 1) * 64 + c * 8);
      }
    }
    #pragma unroll
    for (int kh = 0; kh < 2; ++kh) {
      const int cc = kh * 4 + lg;
      const int sw = (l15 & 7);
      h16x8 af[4], bf[4];
      #pragma unroll
      for (int mt = 0; mt < 4; ++mt) {
        int r = wr * 64 + 16 * mt + l15;
        af[mt] = *(const h16x8*)(Ac + r * 128 + ((cc ^ sw) << 4));
      }
      #pragma unroll
      for (int nt = 0; nt < 4; ++nt) {
        int r = wc * 64 + 16 * nt + l15;
        bf[nt] = *(const h16x8*)(Bc + r * 128 + ((cc ^ sw) << 4));
      }
      __builtin_amdgcn_s_setprio(1);
      #pragma unroll
      for (int mt = 0; mt < 4; ++mt)
        #pragma unroll
        for (int nt = 0; nt < 4; ++nt)
          acc[mt][nt] = MFMA32(af[mt], bf[nt], acc[mt][nt]);
      __builtin_amdgcn_s_setprio(0);
    }
    __syncthreads();
    if (kt < 7) {
      #pragma unroll
      for (int p = 0; p < 8; ++p) {
        int idx = tid + p * 256;
        int r = (idx >> 3) & 127, c = idx & 7;
        char* dst = ((idx < 1024) ? Ac : Bc) + r * 128 + ((c ^ (r & 7)) << 4);
        *(h16x8*)dst = pre[p];
      }
      __syncthreads();
    }
  }
  #pragma unroll
  for (int nt = 0; nt < 4; ++nt) {
    int col = colt * 128 + wc * 64 + nt * 16 + l15;
    float pb = proj_b[col];
    #pragma unroll
    for (int mt = 0; mt < 4; ++mt) {
      int row = rowt * 128 + wr * 64 + mt * 16 + 4 * lg;
      #pragma unroll
      for (int r = 0; r < 4; ++r)
        out[(size_t)(row + r) * 512 + col] = acc[mt][nt][r] + pb;
    }
  }
}

extern "C" void kernel_launch(void* const* d_in, const int* in_sizes, int n_in,
                              void* d_out, int out_size, void* d_ws, size_t ws_size,
                              hipStream_t stream) {
  const float* x          = (const float*)d_in[0];
  const float* qkv_w      = (const float*)d_in[1];
  const float* qkv_b      = (const float*)d_in[2];
  const float* proj_w     = (const float*)d_in[3];
  const float* proj_b     = (const float*)d_in[4];
  const float* bias_table = (const float*)d_in[5];
  float* out = (float*)d_out;

  char* ws = (char*)d_ws;
  h16*   O     = (h16*)ws;
  h16*   w1F   = (h16*)(ws + W1F_OFF);
  h16*   w2T   = (h16*)(ws + W2T_OFF);
  float* biasF = (float*)(ws + BF_OFF);

  wa_prep<<<704, 256, 0, stream>>>(qkv_w, proj_w, bias_table, w1F, w2T, biasF);
  wa_qkv_attn<<<8192, 256, 0, stream>>>(x, qkv_b, w1F, biasF, O);
  wa_proj<<<1568 * 4, 256, 0, stream>>>(O, w2T, proj_b, out);
}